// Round 5
// baseline (255.596 us; speedup 1.0000x reference)
//
#include <hip/hip_runtime.h>

namespace {
constexpr int kInCh  = 64;
constexpr int kOutCh = 64;
constexpr int kK     = 3;
constexpr int kFanIn = 8;
constexpr int kH     = 1024;
constexpr int kTile  = 64;           // h-positions per WAVE-tile
constexpr int kRow   = 72;           // [3]=x[h0-1], [4..67]=body, [68]=x[h0+64]; 72 dwords -> 8-bank row stagger
constexpr int kWaves = 4;            // waves per block (no sharing between them)
constexpr int kBlk   = 64 * kWaves;  // 256
constexpr int kHB    = kH / kTile;   // 16 h-tiles per batch row
constexpr int kGridB = 512;          // 2 blocks/CU (LDS 73.7KB/block) -> 8 autonomous waves/CU
}

struct Tap { int off; float w; };    // off = DWORD offset into a wave's LDS tile

// input fake-quant, INTEGER-valued result in [-128,127]. The *0.0625 scale is
// folded into the tap weight (VERIFIED rounds 2-4, absmax=0.0: pow2 scale, fmaf
// fuses the product — (w*2^-4)*q bit-identical to w*(q*2^-4); chain unchanged).
__device__ __forceinline__ float quant_in_i(float v) {
    float q = rintf(v * 16.0f);
    q = fmaxf(q, -128.0f);
    return fminf(q, 127.0f);
}

// output fake-quant in fp32 (ref conv+quant is fp32; *8 and *0.125 exact pow2)
__device__ __forceinline__ float quant_out(float v) {
    float q = rintf(v * 8.0f);
    q = fmaxf(q, -128.0f);
    q = fminf(q, 127.0f);
    return q * 0.125f;
}

// VERIFIED (absmax=0.0 rounds 1-4): reference == single fp32 FMA chain per output
// in (k-major, ci-minor) tap order. DO NOT change tap ordering or chain structure.
__global__ void prep_taps(const float* __restrict__ weight,
                          const float* __restrict__ mask,
                          Tap* __restrict__ taps) {
    __shared__ unsigned long long bal[3];
    const int o    = blockIdx.x;
    const int j    = threadIdx.x;        // key: k*64 + ci  (wave index == k)
    const int k    = j >> 6;
    const int ci   = j & 63;
    const int idx  = (o * kInCh + ci) * kK + k;   // OIH storage

    const float m = mask[idx];
    const unsigned long long b = __ballot(m != 0.0f);
    if (ci == 0) bal[k] = b;
    __syncthreads();

    const unsigned long long lower = b & ((1ull << ci) - 1ull);
    int rank = __popcll(lower);
    #pragma unroll
    for (int w = 0; w < kK; ++w) if (w < k) rank += __popcll(bal[w]);

    if (m != 0.0f && rank < kFanIn) {
        taps[o * kFanIn + rank].off = ci * kRow + k + 3;        // dword offset
        taps[o * kFanIn + rank].w   = weight[idx] * m * 0.0625f;
    }
    // zero-pad slots beyond the total nonzero count (ws is poisoned 0xAA)
    int total = __popcll(bal[0]) + __popcll(bal[1]) + __popcll(bal[2]);
    if (j >= total && j < kFanIn) {
        taps[o * kFanIn + j].off = 3;
        taps[o * kFanIn + j].w   = 0.0f;
    }
}

__device__ __forceinline__ void issue_loads(const float* __restrict__ x, int tau,
                                            int lane, float4* __restrict__ r,
                                            float& hl, float& hr) {
    const int n  = tau >> 4;                 // kHB = 16
    const int h0 = (tau & (kHB - 1)) * kTile;
    const float* __restrict__ p = x + ((size_t)n * kInCh) * kH + h0;
    #pragma unroll
    for (int i = 0; i < 16; ++i) {
        const int f = i * 64 + lane;         // float4 index: row f>>4 (16 f4/row), col f&15
        r[i] = reinterpret_cast<const float4*>(p + (f >> 4) * kH)[f & 15];
    }
    hl = 0.f; hr = 0.f;
    if (h0 > 0)          hl = p[lane * kH - 1];      // left halo, row = lane
    if (h0 + kTile < kH) hr = p[lane * kH + kTile];  // right halo, row = lane
}

__device__ __forceinline__ void stage(float (* __restrict__ my)[kRow], int lane,
                                      const float4* __restrict__ r, float hl, float hr) {
    #pragma unroll
    for (int i = 0; i < 16; ++i) {
        const int f = i * 64 + lane;
        float4 q;
        q.x = quant_in_i(r[i].x); q.y = quant_in_i(r[i].y);
        q.z = quant_in_i(r[i].z); q.w = quant_in_i(r[i].w);
        *reinterpret_cast<float4*>(&my[f >> 4][4 + (f & 15) * 4]) = q;  // 16B-aligned
    }
    my[lane][3]         = quant_in_i(hl);
    my[lane][4 + kTile] = quant_in_i(hr);
}

// ROUND 5: WAVE-AUTONOMOUS tiles — the convoy killer. Evidence R1-R4: every
// block-barrier structure duty-cycles HBM at ~50% (R4: 8 blk/CU, HBM 3.3TB/s,
// conv 80us; blocks load/compute/retire in lockstep around __syncthreads).
// Here ONE WAVE owns one kTile=64 tile (18KB LDS): stages it, computes all 64
// outputs, NO __syncthreads anywhere -> waves free-run and self-desynchronize,
// HBM demand continuous. Persistent 2048 waves x 4 tiles, per-wave register
// prefetch of next tile (no barriers -> compiler emits counted vmcnt, prefetch
// survives). In-flight ~8 waves x 16KB = 128KB/CU >> 22KB needed for peak BW.
// EXPECTED: OccupancyPercent ~25% (8 waves/CU, LDS-capped) — by design.
__global__ __launch_bounds__(kBlk, 2) void sparse_conv(
        const float* __restrict__ x,
        const Tap*   __restrict__ taps,
        float*       __restrict__ out,
        int nTiles, int strideW) {
    __shared__ float sm[kWaves][kInCh][kRow];   // 73,728 B -> 2 blocks/CU

    const int t    = threadIdx.x;
    const int lane = t & 63;
    const int g    = __builtin_amdgcn_readfirstlane(t >> 6);
    float (* __restrict__ my)[kRow] = sm[g];
    const float* __restrict__ smf = &my[0][0];

    int tau = blockIdx.x * kWaves + g;
    float4 r[16]; float hl, hr;
    if (tau < nTiles) issue_loads(x, tau, lane, r, hl, hr);

    while (tau < nTiles) {
        stage(my, lane, r, hl, hr);          // waits on this tile's loads only
        const int cur = tau;
        tau += strideW;
        if (tau < nTiles) issue_loads(x, tau, lane, r, hl, hr);  // prefetch in flight under compute

        const int n  = cur >> 4;
        const int h0 = (cur & (kHB - 1)) * kTile;
        float* __restrict__ outn = out + ((size_t)n * kOutCh) * kH + h0;

        // 64 outputs, lane does h = h0 + lane. Taps are wave-uniform -> s_load.
        // Single sequential fp32 FMA chain, j ascending (verified order).
        // smf[off+lane]: stride-1 lanes -> 2 lanes/bank = conflict-free.
        #pragma unroll 8
        for (int o = 0; o < kOutCh; ++o) {
            const Tap* __restrict__ tp = taps + o * kFanIn;
            float acc = 0.f;
            #pragma unroll
            for (int j = 0; j < kFanIn; ++j)
                acc = fmaf(tp[j].w, smf[tp[j].off + lane], acc);
            outn[(size_t)o * kH + lane] = quant_out(acc);
        }
    }
}

extern "C" void kernel_launch(void* const* d_in, const int* in_sizes, int n_in,
                              void* d_out, int out_size, void* d_ws, size_t ws_size,
                              hipStream_t stream) {
    const float* x      = (const float*)d_in[0];
    const float* weight = (const float*)d_in[1];
    const float* mask   = (const float*)d_in[2];
    float* out = (float*)d_out;
    Tap* taps = (Tap*)d_ws;   // 64*8*8 B = 4 KiB of workspace

    const int nBatch = in_sizes[0] / (kInCh * kH);   // 512
    const int nTiles = nBatch * kHB;                 // 8192
    const int strideW = kGridB * kWaves;             // 2048 persistent waves

    prep_taps<<<kOutCh, kInCh * kK, 0, stream>>>(weight, mask, taps);
    sparse_conv<<<kGridB, kBlk, 0, stream>>>(x, taps, out, nTiles, strideW);
}

// Round 6
// 240.866 us; speedup vs baseline: 1.0612x; 1.0612x over previous
//
#include <hip/hip_runtime.h>

namespace {
constexpr int kInCh  = 64;
constexpr int kOutCh = 64;
constexpr int kK     = 3;
constexpr int kFanIn = 8;
constexpr int kH     = 1024;
constexpr int kTile  = 64;           // h-positions per tile
constexpr int kRow   = 72;           // [3]=x[h0-1], [4..67]=body, [68]=x[h0+64]
constexpr int kBlk   = 512;          // 8 waves
constexpr int kHB    = kH / kTile;   // 16 h-tiles per batch row
constexpr int kGridB = 2048;         // 4 blocks/CU (LDS 36.9KB) -> 32 waves/CU (cap); 4 tiles/block
}

struct Tap { int off; float w; };    // off = DWORD offset into one LDS tile buffer

// input fake-quant, INTEGER-valued result in [-128,127]. The *0.0625 scale is
// folded into the tap weight (VERIFIED rounds 2-5, absmax=0.0: pow2 scale, fmaf
// fuses the product — (w*2^-4)*q bit-identical to w*(q*2^-4); chain unchanged).
__device__ __forceinline__ float quant_in_i(float v) {
    float q = rintf(v * 16.0f);
    q = fmaxf(q, -128.0f);
    return fminf(q, 127.0f);
}

// output fake-quant in fp32 (ref conv+quant is fp32; *8 and *0.125 exact pow2)
__device__ __forceinline__ float quant_out(float v) {
    float q = rintf(v * 8.0f);
    q = fmaxf(q, -128.0f);
    q = fminf(q, 127.0f);
    return q * 0.125f;
}

// VERIFIED (absmax=0.0 rounds 1-5): reference == single fp32 FMA chain per output
// in (k-major, ci-minor) tap order. DO NOT change tap ordering or chain structure.
__global__ void prep_taps(const float* __restrict__ weight,
                          const float* __restrict__ mask,
                          Tap* __restrict__ taps) {
    __shared__ unsigned long long bal[3];
    const int o    = blockIdx.x;
    const int j    = threadIdx.x;        // key: k*64 + ci  (wave index == k)
    const int k    = j >> 6;
    const int ci   = j & 63;
    const int idx  = (o * kInCh + ci) * kK + k;   // OIH storage

    const float m = mask[idx];
    const unsigned long long b = __ballot(m != 0.0f);
    if (ci == 0) bal[k] = b;
    __syncthreads();

    const unsigned long long lower = b & ((1ull << ci) - 1ull);
    int rank = __popcll(lower);
    #pragma unroll
    for (int w = 0; w < kK; ++w) if (w < k) rank += __popcll(bal[w]);

    if (m != 0.0f && rank < kFanIn) {
        taps[o * kFanIn + rank].off = ci * kRow + k + 3;        // dword offset
        taps[o * kFanIn + rank].w   = weight[idx] * m * 0.0625f;
    }
    // zero-pad slots beyond the total nonzero count (ws is poisoned 0xAA)
    int total = __popcll(bal[0]) + __popcll(bal[1]) + __popcll(bal[2]);
    if (j >= total && j < kFanIn) {
        taps[o * kFanIn + j].off = 3;
        taps[o * kFanIn + j].w   = 0.0f;
    }
}

// ROUND 6: DOUBLE-BUFFERED LDS at full occupancy — overlap the two ~40us pipes.
// Evidence R1-R5: conv time tracks waves/CU (32w->80us, 16w->106, 8w->106);
// R4's 80us = HBM phase (~41us total) + LDS-read phase (~40us: 4.19M ds_read_b32
// x 5.8cyc) run SERIALLY per CU (barrier-locked identical blocks convoy).
// Fix: 2 x 18.4KB buffers, 4 blocks/CU (32 waves = cap). Per tile: stage buf[p]
// -> ONE barrier -> issue next tile's loads AFTER the barrier (so the barrier's
// vmcnt(0) drains only old output stores, never the prefetch — R2's failure
// inverted) -> compute buf[p] while loads fly. Buffer-safe with one barrier:
// reaching stage(i+2) requires passing barrier(i+1) which requires all waves
// past compute(i).
__global__ __launch_bounds__(kBlk, 8) void sparse_conv(
        const float* __restrict__ x,
        const Tap*   __restrict__ taps,
        float*       __restrict__ out,
        int nTiles, int stride) {
    __shared__ float sm[2][kInCh * kRow];   // 2 x 18,432 B = 36,864 B

    const int t    = threadIdx.x;
    const int lane = t & 63;
    const int g    = __builtin_amdgcn_readfirstlane(t >> 6);   // wave = o-group (0..7)
    const int ci0  = t >> 4;             // body row for chunk 0 (0..31); chunk 1: +32
    const int c4   = t & 15;             // float4 column (16 per row)

    float4 r0, r1; float hl = 0.f;
    int tau = blockIdx.x;

#define ISSUE(TAU)                                                                 \
    {                                                                              \
        const int n_  = (TAU) >> 4;                                                \
        const int h0_ = ((TAU) & (kHB - 1)) * kTile;                               \
        const float* __restrict__ p_ = x + ((size_t)n_ * kInCh) * kH + h0_;        \
        r0 = reinterpret_cast<const float4*>(p_ + ci0 * kH)[c4];                   \
        r1 = reinterpret_cast<const float4*>(p_ + (ci0 + 32) * kH)[c4];            \
        hl = 0.f;                                                                  \
        if (t < 64)       { if (h0_ > 0)          hl = p_[t * kH - 1]; }           \
        else if (t < 128) { if (h0_ + kTile < kH) hl = p_[(t - 64) * kH + kTile]; }\
    }

    ISSUE(tau);                          // prologue loads (unhidden once, /4 tiles)
    int p = 0;

    while (tau < nTiles) {
        float* __restrict__ buf = sm[p];
        {   // ---- stage: waits THIS tile's loads (counted vmcnt; later stores
            //      in FIFO don't block), quantize once on store ----
            float4 q;
            q.x = quant_in_i(r0.x); q.y = quant_in_i(r0.y);
            q.z = quant_in_i(r0.z); q.w = quant_in_i(r0.w);
            reinterpret_cast<float4*>(&buf[ci0 * kRow + 4])[c4] = q;
            q.x = quant_in_i(r1.x); q.y = quant_in_i(r1.y);
            q.z = quant_in_i(r1.z); q.w = quant_in_i(r1.w);
            reinterpret_cast<float4*>(&buf[(ci0 + 32) * kRow + 4])[c4] = q;
            if (t < 64)       buf[t * kRow + 3] = quant_in_i(hl);
            else if (t < 128) buf[(t - 64) * kRow + 4 + kTile] = quant_in_i(hl);
        }
        __syncthreads();                 // drains only OLD stores; prefetch not yet issued

        const int cur = tau;
        tau += stride;
        if (tau < nTiles) ISSUE(tau);    // prefetch AFTER barrier -> survives it

        const int n  = cur >> 4;
        const int h0 = (cur & (kHB - 1)) * kTile;
        float* __restrict__ outn = out + ((size_t)n * kOutCh) * kH + h0;

        // ---- compute (overlaps in-flight prefetch): wave g owns outputs
        //      g*8..g*8+7; lane does h = h0+lane. Taps wave-uniform -> s_load.
        //      Single sequential fp32 FMA chain, j ascending (verified order).
        //      buf[off+lane]: stride-1 lanes -> 2 lanes/bank = conflict-free. ----
        #pragma unroll 4
        for (int oo = 0; oo < 8; ++oo) {
            const int o = g * 8 + oo;
            const Tap* __restrict__ tp = taps + o * kFanIn;
            float acc = 0.f;
            #pragma unroll
            for (int j = 0; j < kFanIn; ++j)
                acc = fmaf(tp[j].w, buf[tp[j].off + lane], acc);
            outn[(size_t)o * kH + lane] = quant_out(acc);
        }
        p ^= 1;
    }
#undef ISSUE
}

extern "C" void kernel_launch(void* const* d_in, const int* in_sizes, int n_in,
                              void* d_out, int out_size, void* d_ws, size_t ws_size,
                              hipStream_t stream) {
    const float* x      = (const float*)d_in[0];
    const float* weight = (const float*)d_in[1];
    const float* mask   = (const float*)d_in[2];
    float* out = (float*)d_out;
    Tap* taps = (Tap*)d_ws;   // 64*8*8 B = 4 KiB of workspace

    const int nBatch = in_sizes[0] / (kInCh * kH);   // 512
    const int nTiles = nBatch * kHB;                 // 8192
    const int grid   = nTiles < kGridB ? nTiles : kGridB;

    prep_taps<<<kOutCh, kInCh * kK, 0, stream>>>(weight, mask, taps);
    sparse_conv<<<grid, kBlk, 0, stream>>>(x, taps, out, nTiles, grid);
}